// Round 19
// baseline (210.669 us; speedup 1.0000x reference)
//
#include <hip/hip_runtime.h>

// 1-NN via 1-term bf16 MFMA screen (bias-fused, index-stuffed keys, TOP-3) +
// provable per-query Cauchy-Schwarz radius + exact fp32 pair/rescore tail.
// argmin_j ||x-y_j||^2 == argmin_j (0.5||y_j||^2 - x.y_j).
// Pass A: MFMA emits key_j = 512 + h_j - xhi.yhi (C init = h+512, A = -xhi);
//   low 10 mantissa bits carry slice-local j (v_bfi); med3 cascade keeps a
//   sorted per-lane top-3, lane-16 merge network reduces per query.
// Pass B: thr = m+epsq, epsq = 2.02*CS + 0.08. pv3>thr -> 1-2 explicit pairs
//   (stuffed idx); pv3<=thr -> slice rescan (task-parallel).
//
// Round 19: (a) revert to TOP-3 (round 18's top-2 grew the rescan tail +20us);
// (b) NSLICE 32->64 (SLICE=512, grid 2048): round 17's nnA lost ~30% to grid
// quantization (1024 blocks at 3/CU = 768 resident -> 33%-occupancy straggler
// phase; Occupancy counter 26% vs 37.5% cap). 2048 finer blocks cut the loss
// to ~12%, and rescans get 2x finer and rarer. XCD pin dropped (round-14 null).

#define NQ 8192
#define NM 32768
#define ND 128
#define BT 256                // nnA block: 4 waves
#define NSLICE 64
#define SLICE (NM / NSLICE)   // 512 rows -> 8 chunks of 64
#define QW 64                 // queries per wave
#define QB (QW * 4)           // 256 queries per block
#define CAPS 131072
#define CAPR 32768
#define PREP_YB 512
#define PREP_XB 128

using bf16x8 = __attribute__((ext_vector_type(8))) short;
using f32x4  = __attribute__((ext_vector_type(4))) float;

__device__ __forceinline__ unsigned short bf16r(float f) {
  unsigned u = __float_as_uint(f);
  u += 0x7FFFu + ((u >> 16) & 1u);
  return (unsigned short)(u >> 16);
}
__device__ __forceinline__ float bf2f(unsigned short h) {
  return __uint_as_float(((unsigned)h) << 16);
}
__device__ __forceinline__ unsigned long long packsd(float s, int j) {
  unsigned u = __float_as_uint(s);
  u ^= (u & 0x80000000u) ? 0xFFFFFFFFu : 0x80000000u;  // monotone float->uint
  return (((unsigned long long)u) << 32) | (unsigned)j;
}
__device__ __forceinline__ void gload_lds16(const void* g, void* l) {
  __builtin_amdgcn_global_load_lds(
      (const __attribute__((address_space(1))) void*)g,
      (__attribute__((address_space(3))) void*)l, 16, 0, 0);
}

// ---- prep: y -> packed bf16 hi ypk[rg][ks][lane][8], h[j]=0.5||y||^2,
//      global maxes of ||y||^2/||ylo||^2; x -> per-query ||x||^2, ||xlo||^2.
__global__ __launch_bounds__(256) void prep_kernel(
    const float* __restrict__ y, const float* __restrict__ x,
    unsigned short* __restrict__ ypk, float* __restrict__ h,
    float* __restrict__ x2, float* __restrict__ xlo2,
    unsigned* __restrict__ scal, int* __restrict__ cnts) {
  const int wv = threadIdx.x >> 6, l = threadIdx.x & 63;
  if (blockIdx.x == 0 && threadIdx.x == 0) { cnts[0] = 0; cnts[1] = 0; }
  if (blockIdx.x < PREP_YB) {
    __shared__ float bm[4][2];
    float ms = 0.f, mslo = 0.f;
    const int j00 = blockIdx.x * 64 + wv * 16;
#pragma unroll
    for (int r = 0; r < 16; ++r) {
      const int j = j00 + r;
      const float2 v = *(const float2*)(y + (size_t)j * ND + l * 2);
      const unsigned short hb0 = bf16r(v.x), hb1 = bf16r(v.y);
      const float lo0 = v.x - bf2f(hb0), lo1 = v.y - bf2f(hb1);
      const int c0 = l * 2;
      const int idx = ((j >> 4) * 2048) + ((c0 >> 5) * 512) +
                      ((((c0 >> 3) & 3) * 16 + (j & 15)) * 8) + (c0 & 7);
      *(unsigned*)&ypk[idx] = (unsigned)hb0 | ((unsigned)hb1 << 16);
      float s = fmaf(v.y, v.y, v.x * v.x);
      float slo = fmaf(lo1, lo1, lo0 * lo0);
      for (int off = 32; off; off >>= 1) {
        s += __shfl_xor(s, off);
        slo += __shfl_xor(slo, off);
      }
      if (l == 0) h[j] = 0.5f * s;
      ms = fmaxf(ms, s);
      mslo = fmaxf(mslo, slo);
    }
    if (l == 0) { bm[wv][0] = ms; bm[wv][1] = mslo; }
    __syncthreads();
    if (threadIdx.x == 0) {
      float a = bm[0][0], b = bm[0][1];
#pragma unroll
      for (int w2 = 1; w2 < 4; ++w2) { a = fmaxf(a, bm[w2][0]); b = fmaxf(b, bm[w2][1]); }
      atomicMax(&scal[0], __float_as_uint(a));
      atomicMax(&scal[1], __float_as_uint(b));
    }
  } else {
    const int q00 = (blockIdx.x - PREP_YB) * 64 + wv * 16;
#pragma unroll
    for (int r = 0; r < 16; ++r) {
      const int q = q00 + r;
      const float2 v = *(const float2*)(x + (size_t)q * ND + l * 2);
      const unsigned short hb0 = bf16r(v.x), hb1 = bf16r(v.y);
      const float lo0 = v.x - bf2f(hb0), lo1 = v.y - bf2f(hb1);
      float s = fmaf(v.y, v.y, v.x * v.x);
      float slo = fmaf(lo1, lo1, lo0 * lo0);
      for (int off = 32; off; off >>= 1) {
        s += __shfl_xor(s, off);
        slo += __shfl_xor(slo, off);
      }
      if (l == 0) { x2[q] = s; xlo2[q] = slo; }
    }
  }
}

// ---- pass A ----
// LDS chunk (shorts): [rg(4)][ks(4)][lane(64)][8] = 8192 shorts = 16KB.
#define LDFR(FH, ST) do {                                                      \
    _Pragma("unroll")                                                          \
    for (int ks = 0; ks < 4; ++ks)                                            \
      FH[ks] = *(const bf16x8*)&bufc[(ST) * 2048 + ks * 512 + lane * 8];       \
  } while (0)

#define MFST(FH, ST) do {                                                      \
    const float K_ = hv[ST];                                                   \
    f32x4 a0 = {K_, K_, K_, K_}, a1 = {K_, K_, K_, K_};                        \
    f32x4 a2 = {K_, K_, K_, K_}, a3 = {K_, K_, K_, K_};                        \
    __builtin_amdgcn_s_setprio(1);                                             \
    _Pragma("unroll")                                                          \
    for (int ks = 0; ks < 4; ++ks) {                                           \
      a0 = __builtin_amdgcn_mfma_f32_16x16x32_bf16(xn_[0][ks], FH[ks], a0, 0, 0, 0); \
      a1 = __builtin_amdgcn_mfma_f32_16x16x32_bf16(xn_[1][ks], FH[ks], a1, 0, 0, 0); \
      a2 = __builtin_amdgcn_mfma_f32_16x16x32_bf16(xn_[2][ks], FH[ks], a2, 0, 0, 0); \
      a3 = __builtin_amdgcn_mfma_f32_16x16x32_bf16(xn_[3][ks], FH[ks], a3, 0, 0, 0); \
    }                                                                          \
    __builtin_amdgcn_s_setprio(0);                                             \
    const unsigned jc_ = (unsigned)((it * 64 + (ST) * 16 + l15) & (SLICE - 1));\
    _Pragma("unroll")                                                          \
    for (int p = 0; p < 16; ++p) {                                             \
      const float aa = (p < 4) ? a0[p & 3] : (p < 8) ? a1[p & 3]               \
                       : (p < 12) ? a2[p & 3] : a3[p & 3];                     \
      const float key = __uint_as_float(                                       \
          (__float_as_uint(aa) & 0xFFFFFC00u) | jc_);  /* v_bfi */             \
      v3[p] = __builtin_amdgcn_fmed3f(v2[p], v3[p], key);                      \
      v2[p] = __builtin_amdgcn_fmed3f(v1[p], v2[p], key);                      \
      v1[p] = fminf(v1[p], key);                                               \
    }                                                                          \
  } while (0)

__global__ __launch_bounds__(BT, 3) void nnA_mfma(
    const float* __restrict__ x, const unsigned short* __restrict__ ypk,
    const float* __restrict__ h,
    float* __restrict__ pv1, float* __restrict__ pv2, float* __restrict__ pv3) {
  __shared__ unsigned short yl2[2][8192];  // double-buffered 64-row chunk, 4-wave shared
  const int t = threadIdx.x, lane = t & 63, w = t >> 6;
  const int l15 = lane & 15, lg = lane >> 4;
  const int slice = blockIdx.x & (NSLICE - 1);
  const int q0 = (blockIdx.x >> 6) * QB + w * QW;  // this wave's 64 queries

  // NEGATED x hi fragments (A-frag row=query l15, k=ks*32+lg*8+i)
  bf16x8 xn_[4][4];
#pragma unroll
  for (int qt = 0; qt < 4; ++qt)
#pragma unroll
    for (int ks = 0; ks < 4; ++ks) {
      const float* xp = x + (size_t)(q0 + qt * 16 + l15) * ND + ks * 32 + lg * 8;
      const float4 f0 = *(const float4*)xp;
      const float4 f1 = *(const float4*)(xp + 4);
      const float ff[8] = {f0.x, f0.y, f0.z, f0.w, f1.x, f1.y, f1.z, f1.w};
      bf16x8 vh;
#pragma unroll
      for (int i = 0; i < 8; ++i)
        vh[i] = (short)(bf16r(ff[i]) ^ 0x8000u);  // bf16 negate = sign flip
      xn_[qt][ks] = vh;
    }

  float v1[16], v2[16], v3[16];
#pragma unroll
  for (int p = 0; p < 16; ++p) { v1[p] = 3.4e38f; v2[p] = 3.4e38f; v3[p] = 3.4e38f; }

  const size_t sbase = (size_t)slice * (SLICE / 16) * 2048;
  // Prologue: 4 waves cooperatively stage chunk 0 (each 2048 shorts).
  {
    const unsigned short* src = ypk + sbase + w * 2048 + lane * 8;
#pragma unroll
    for (int s = 0; s < 4; ++s)
      gload_lds16(src + s * 512, &yl2[0][w * 2048 + s * 512]);
  }
  __syncthreads();

#pragma unroll 1
  for (int it = 0; it < SLICE / 64; ++it) {
    const int cur = it & 1;
    if (it < SLICE / 64 - 1) {
      const unsigned short* src =
          ypk + sbase + (size_t)(it + 1) * 8192 + w * 2048 + lane * 8;
      unsigned short* dst = &yl2[cur ^ 1][w * 2048];
#pragma unroll
      for (int s = 0; s < 4; ++s)
        gload_lds16(src + s * 512, dst + s * 512);
    }
    const int jb = slice * SLICE + it * 64;
    float hv[4];
#pragma unroll
    for (int st = 0; st < 4; ++st) hv[st] = h[jb + st * 16 + l15] + 512.0f;

    const unsigned short* __restrict__ bufc = &yl2[cur][0];
    bf16x8 FA[4];
    LDFR(FA, 0); MFST(FA, 0);
    LDFR(FA, 1); MFST(FA, 1);
    LDFR(FA, 2); MFST(FA, 2);
    LDFR(FA, 3); MFST(FA, 3);
    __syncthreads();
  }

  // Lane-16 top-3 merge network (keys positive w/ stuffed idx: min = lex min).
#pragma unroll
  for (int p = 0; p < 16; ++p) {
    float m1 = v1[p], m2 = v2[p], m3 = v3[p];
    for (int off = 1; off < 16; off <<= 1) {
      const float o1 = __shfl_xor(m1, off);
      const float o2 = __shfl_xor(m2, off);
      const float o3 = __shfl_xor(m3, off);
      const float n1 = fminf(m1, o1);
      const float n2 = __builtin_amdgcn_fmed3f(m1, o1, fminf(m2, o2));
      const float n3 = fminf(__builtin_amdgcn_fmed3f(m2, o2, fmaxf(m1, o1)),
                             fminf(m3, o3));
      m1 = n1; m2 = n2; m3 = n3;
    }
    if (l15 == 0) {
      const int q = q0 + (p >> 2) * 16 + lg * 4 + (p & 3);
      // TRANSPOSED layout [slice][NQ]: nnB reads are coalesced.
      pv1[(size_t)slice * NQ + q] = m1;
      pv2[(size_t)slice * NQ + q] = m2;
      pv3[(size_t)slice * NQ + q] = m3;
    }
  }
}

// exact fp32 key; k-ascending serial chain (nnB overflow path only)
__device__ __forceinline__ unsigned long long exact_key(
    const float* __restrict__ x, const float* __restrict__ y,
    const float* __restrict__ h, int q, int j) {
  const float* xp = x + (size_t)q * ND;
  const float* yp = y + (size_t)j * ND;
  float dot = 0.f;
#pragma unroll
  for (int k = 0; k < ND; ++k) dot = fmaf(xp[k], yp[k], dot);
  return packsd(h[j] - dot, j);
}

// ---- pass B: classify; explicit pairs from stuffed indices; rare rescans ----
__global__ void nnB_kernel(const float* __restrict__ x, const float* __restrict__ y,
                           const float* __restrict__ h, const float* __restrict__ lab,
                           const float* __restrict__ pv1, const float* __restrict__ pv2,
                           const float* __restrict__ pv3,
                           const float* __restrict__ x2, const float* __restrict__ xlo2,
                           const unsigned* __restrict__ scal,
                           float* __restrict__ out,
                           unsigned long long* __restrict__ packed,
                           int* __restrict__ mode, int* __restrict__ wlS,
                           int* __restrict__ wlR, int* __restrict__ cnts) {
  const int q = blockIdx.x * blockDim.x + threadIdx.x;
  if (q >= NQ) return;
  const float maxY = sqrtf(__uint_as_float(scal[0]));
  const float maxYlo = sqrtf(__uint_as_float(scal[1]));
  const float ex = sqrtf(x2[q]), exl = sqrtf(xlo2[q]);
  // hard bound: |key-(512+D)| <= CS; +0.08 = proven key-quant slack + margin.
  const float epsq = 2.0f * ((ex + exl) * maxYlo + exl * maxY) * 1.01f + 0.08f;
  float m = 3.4e38f;
  for (int s = 0; s < NSLICE; ++s) m = fminf(m, pv1[(size_t)s * NQ + q]);
  const float thr = m + epsq;
  int pj[14], rs[12], np = 0, nr = 0, xr = 0, bad = 0;
  for (int s = 0; s < NSLICE; ++s) {
    const float p1 = pv1[(size_t)s * NQ + q];
    if (p1 > thr) continue;
    bool resc = (pv3[(size_t)s * NQ + q] <= thr);  // >=3 candidates in slice
    if (!resc) {
      const float p2 = pv2[(size_t)s * NQ + q];
      const int extra = (p2 <= thr) ? 1 : 0;
      if (np + 1 + extra <= 14) {
        pj[np++] = s * SLICE + (int)(__float_as_uint(p1) & (SLICE - 1));
        if (extra) pj[np++] = s * SLICE + (int)(__float_as_uint(p2) & (SLICE - 1));
      } else {
        resc = true;  // pair array full (never in practice): rescan covers it
      }
    }
    if (resc) {
      if (nr < 12) {
        rs[nr++] = s;
      } else {  // rescan array full (never): push individually
        const int b = atomicAdd(&cnts[1], 1);
        if (b < CAPR) wlR[b] = (q << 6) | s; else bad = 1;
        xr = 1;
      }
    }
  }
  if (nr == 0 && xr == 0 && np == 1) { out[q] = lab[pj[0]]; mode[q] = 0; return; }
  mode[q] = 1;
  packed[q] = ~0ull;
  const int baseS = atomicAdd(&cnts[0], np);
  for (int i = 0; i < np; ++i)
    if (baseS + i < CAPS) wlS[baseS + i] = (q << 15) | pj[i];
  const int baseR = atomicAdd(&cnts[1], nr);
  for (int i = 0; i < nr; ++i)
    if (baseR + i < CAPR) wlR[baseR + i] = (q << 6) | rs[i];
  if (bad || baseS + np > CAPS || baseR + nr > CAPR) {
    // absolute last resort (astronomically improbable): serial exact over
    // every candidate slice -- covers all dropped entries.
    unsigned long long b = ~0ull;
    for (int s = 0; s < NSLICE; ++s) {
      if (pv1[(size_t)s * NQ + q] <= thr) {
        for (int j = s * SLICE; j < s * SLICE + SLICE; ++j) {
          const unsigned long long k = exact_key(x, y, h, q, j);
          b = k < b ? k : b;
        }
      }
    }
    out[q] = lab[(unsigned)(b & 0xFFFFFFFFull)];
    mode[q] = 0;
  }
}

// ---- pass T: fused tail. All waves: drain pair list (wave dot each), then
//      rescan tasks ((entry x 32 row-groups), 16 coalesced row dots, ILP).
__global__ __launch_bounds__(256) void nnT_kernel(
    const float* __restrict__ x, const float* __restrict__ y,
    const float* __restrict__ h, const int* __restrict__ wlS,
    const int* __restrict__ wlR, const int* __restrict__ cnts,
    unsigned long long* __restrict__ packed) {
  const int l = threadIdx.x & 63;
  const int wid = (blockIdx.x * blockDim.x + threadIdx.x) >> 6;
  const int nw = (gridDim.x * blockDim.x) >> 6;
  int nS = cnts[0];
  if (nS > CAPS) nS = CAPS;
  for (int e = wid; e < nS; e += nw) {
    const int v = wlS[e];
    const int q = v >> 15, j = v & (NM - 1);
    const float2 xv = *(const float2*)(x + (size_t)q * ND + l * 2);
    const float2 yv = *(const float2*)(y + (size_t)j * ND + l * 2);
    float d = fmaf(xv.y, yv.y, xv.x * yv.x);
    for (int off = 32; off; off >>= 1) d += __shfl_xor(d, off);
    if (l == 0) atomicMin(packed + q, packsd(h[j] - d, j));
  }
  int nR = cnts[1];
  if (nR > CAPR) nR = CAPR;
  const long long ntask = (long long)nR * (SLICE / 16);
  for (long long tsk = wid; tsk < ntask; tsk += nw) {
    const int e = (int)(tsk >> 5), rg = (int)(tsk & 31);
    const int v = wlR[e], q = v >> 6, sl = v & (NSLICE - 1);
    const float2 xv = *(const float2*)(x + (size_t)q * ND + l * 2);
    const int j0 = sl * SLICE + rg * 16;
    unsigned long long best = ~0ull;
#pragma unroll
    for (int r = 0; r < 16; ++r) {
      const int j = j0 + r;
      const float2 yv = *(const float2*)(y + (size_t)j * ND + l * 2);
      float d = fmaf(xv.y, yv.y, xv.x * yv.x);
      for (int off = 32; off; off >>= 1) d += __shfl_xor(d, off);
      const unsigned long long kk = packsd(h[j] - d, j);
      if (kk < best) best = kk;
    }
    if (l == 0) atomicMin(packed + q, best);
  }
}

// ---- pass D: finalize pending queries ----
__global__ void nnD_kernel(const unsigned long long* __restrict__ packed,
                           const int* __restrict__ mode,
                           const float* __restrict__ lab, float* __restrict__ out) {
  const int q = blockIdx.x * blockDim.x + threadIdx.x;
  if (q >= NQ) return;
  if (mode[q]) out[q] = lab[(unsigned)(packed[q] & 0xFFFFFFFFull)];
}

// ---- fallback (round-2 kernel, known-passing) ----
__global__ void hrow_fb(const float* __restrict__ y, float* __restrict__ h) {
  const int j = blockIdx.x * blockDim.x + threadIdx.x;
  if (j >= NM) return;
  const float4* __restrict__ yp = (const float4*)(y + (size_t)j * ND);
  float s = 0.f;
#pragma unroll
  for (int u = 0; u < ND / 4; ++u) {
    const float4 v = yp[u];
    s = fmaf(v.x, v.x, s); s = fmaf(v.y, v.y, s);
    s = fmaf(v.z, v.z, s); s = fmaf(v.w, v.w, s);
  }
  h[j] = 0.5f * s;
}

template <int USE_H>
__global__ __launch_bounds__(256, 2) void nn_fallback(
    const float* __restrict__ x, const float* __restrict__ y,
    const float* __restrict__ lab, const float* __restrict__ h,
    float* __restrict__ out) {
  const int t = threadIdx.x;
  const int q0 = blockIdx.x * 16;
  float bv[16]; int bi[16];
#pragma unroll
  for (int q = 0; q < 16; ++q) { bv[q] = 3.4e38f; bi[q] = 0; }
  for (int it = 0; it < NM / 512; ++it) {
    const int j0 = it * 512 + t, j1 = j0 + 256;
    const float4* __restrict__ yp0 = (const float4*)(y + (size_t)j0 * ND);
    const float4* __restrict__ yp1 = (const float4*)(y + (size_t)j1 * ND);
    float acc0[16], acc1[16];
#pragma unroll
    for (int q = 0; q < 16; ++q) { acc0[q] = 0.f; acc1[q] = 0.f; }
    float y20 = 0.f, y21 = 0.f;
#pragma unroll 1
    for (int kc = 0; kc < 4; ++kc) {
      float4 a0[8], a1[8];
#pragma unroll
      for (int u = 0; u < 8; ++u) { a0[u] = yp0[kc * 8 + u]; a1[u] = yp1[kc * 8 + u]; }
      if (USE_H == 0) {
#pragma unroll
        for (int u = 0; u < 8; ++u) {
          y20 = fmaf(a0[u].x, a0[u].x, y20); y20 = fmaf(a0[u].y, a0[u].y, y20);
          y20 = fmaf(a0[u].z, a0[u].z, y20); y20 = fmaf(a0[u].w, a0[u].w, y20);
          y21 = fmaf(a1[u].x, a1[u].x, y21); y21 = fmaf(a1[u].y, a1[u].y, y21);
          y21 = fmaf(a1[u].z, a1[u].z, y21); y21 = fmaf(a1[u].w, a1[u].w, y21);
        }
      }
#pragma unroll
      for (int q = 0; q < 16; ++q) {
        const float* __restrict__ xq = x + (size_t)(q0 + q) * ND + kc * 32;
        float s0 = acc0[q], s1 = acc1[q];
#pragma unroll
        for (int u = 0; u < 8; ++u) {
          const float4 xv = *(const float4*)(xq + u * 4);
          s0 = fmaf(a0[u].x, xv.x, s0); s0 = fmaf(a0[u].y, xv.y, s0);
          s0 = fmaf(a0[u].z, xv.z, s0); s0 = fmaf(a0[u].w, xv.w, s0);
          s1 = fmaf(a1[u].x, xv.x, s1); s1 = fmaf(a1[u].y, xv.y, s1);
          s1 = fmaf(a1[u].z, xv.z, s1); s1 = fmaf(a1[u].w, xv.w, s1);
        }
        acc0[q] = s0; acc1[q] = s1;
      }
    }
    float h0, h1;
    if (USE_H) { h0 = h[j0]; h1 = h[j1]; }
    else { h0 = 0.5f * y20; h1 = 0.5f * y21; }
#pragma unroll
    for (int q = 0; q < 16; ++q) {
      const float s0 = h0 - acc0[q], s1 = h1 - acc1[q];
      if (s0 < bv[q]) { bv[q] = s0; bi[q] = j0; }
      if (s1 < bv[q]) { bv[q] = s1; bi[q] = j1; }
    }
  }
  __shared__ float rv[4][16];
  __shared__ int ri[4][16];
  const int lane = t & 63, w = t >> 6;
#pragma unroll
  for (int q = 0; q < 16; ++q) {
    float v = bv[q]; int ixq = bi[q];
    for (int off = 32; off; off >>= 1) {
      const float ov = __shfl_down(v, off);
      const int oi = __shfl_down(ixq, off);
      if (ov < v || (ov == v && oi < ixq)) { v = ov; ixq = oi; }
    }
    if (lane == 0) { rv[w][q] = v; ri[w][q] = ixq; }
  }
  __syncthreads();
  if (t < 16) {
    float v = rv[0][t]; int ixq = ri[0][t];
#pragma unroll
    for (int w2 = 1; w2 < 4; ++w2) {
      const float ov = rv[w2][t]; const int oi = ri[w2][t];
      if (ov < v || (ov == v && oi < ixq)) { v = ov; ixq = oi; }
    }
    out[q0 + t] = lab[ixq];
  }
}

extern "C" void kernel_launch(void* const* d_in, const int* in_sizes, int n_in,
                              void* d_out, int out_size, void* d_ws, size_t ws_size,
                              hipStream_t stream) {
  const float* x = (const float*)d_in[0];
  const float* y = (const float*)d_in[1];
  const float* lab = (const float*)d_in[2];
  float* out = (float*)d_out;

  const size_t o_ypk = 0;                                // 8 MB hi-only packed
  const size_t o_h   = o_ypk + (size_t)NM * ND * 2;
  const size_t o_x2  = o_h + (size_t)NM * 4;
  const size_t o_xl2 = o_x2 + (size_t)NQ * 4;
  const size_t o_sc  = o_xl2 + (size_t)NQ * 4;
  const size_t o_p1  = o_sc + 16;
  const size_t o_p2  = o_p1 + (size_t)NQ * NSLICE * 4;   // 2 MB each
  const size_t o_p3  = o_p2 + (size_t)NQ * NSLICE * 4;
  const size_t o_pk  = o_p3 + (size_t)NQ * NSLICE * 4;
  const size_t o_wlS = o_pk + (size_t)NQ * 8;
  const size_t o_wlR = o_wlS + (size_t)CAPS * 4;
  const size_t o_md  = o_wlR + (size_t)CAPR * 4;
  const size_t o_ct  = o_md + (size_t)NQ * 4;
  const size_t need  = o_ct + 16;

  if (ws_size >= need) {
    char* W = (char*)d_ws;
    unsigned short* ypk = (unsigned short*)(W + o_ypk);
    float* h = (float*)(W + o_h);
    float* x2 = (float*)(W + o_x2);
    float* xlo2 = (float*)(W + o_xl2);
    unsigned* scal = (unsigned*)(W + o_sc);
    float* pv1 = (float*)(W + o_p1);
    float* pv2 = (float*)(W + o_p2);
    float* pv3 = (float*)(W + o_p3);
    unsigned long long* packed = (unsigned long long*)(W + o_pk);
    int* wlS = (int*)(W + o_wlS);
    int* wlR = (int*)(W + o_wlR);
    int* mode = (int*)(W + o_md);
    int* cnts = (int*)(W + o_ct);
    hipMemsetAsync(scal, 0, 16, stream);
    prep_kernel<<<PREP_YB + PREP_XB, 256, 0, stream>>>(y, x, ypk, h, x2, xlo2,
                                                       scal, cnts);
    nnA_mfma<<<(NQ / QB) * NSLICE, BT, 0, stream>>>(x, ypk, h, pv1, pv2, pv3);
    nnB_kernel<<<NQ / 256, 256, 0, stream>>>(x, y, h, lab, pv1, pv2, pv3,
                                             x2, xlo2, scal, out, packed, mode,
                                             wlS, wlR, cnts);
    nnT_kernel<<<256, 256, 0, stream>>>(x, y, h, wlS, wlR, cnts, packed);
    nnD_kernel<<<NQ / 256, 256, 0, stream>>>(packed, mode, lab, out);
  } else if (ws_size >= (size_t)NM * 4) {
    float* h = (float*)d_ws;
    hrow_fb<<<NM / 256, 256, 0, stream>>>(y, h);
    nn_fallback<1><<<NQ / 16, 256, 0, stream>>>(x, y, lab, h, out);
  } else {
    nn_fallback<0><<<NQ / 16, 256, 0, stream>>>(x, y, lab, nullptr, out);
  }
}

// Round 20
// 165.252 us; speedup vs baseline: 1.2748x; 1.2748x over previous
//
#include <hip/hip_runtime.h>

// 1-NN via 1-term bf16 MFMA screen (bias-fused, index-stuffed keys, TOP-3) +
// provable per-query Cauchy-Schwarz radius + exact fp32 pair/rescore tail.
// argmin_j ||x-y_j||^2 == argmin_j (0.5||y_j||^2 - x.y_j).
// Pass A: MFMA emits key_j = 512 + h_j - xhi.yhi (C init = h+512, A = -xhi);
//   low 10 mantissa bits carry slice-local j (v_bfi); med3 cascade keeps a
//   sorted per-lane top-3, lane-16 merge network reduces per query.
// Pass B: thr = m+epsq, epsq = 2.02*CS + 0.08 (hard bound + proven key-quant
//   slack). pv3>thr -> 1-2 explicit pairs; pv3<=thr (rare) -> slice rescan.
//
// Round 20: REVERT to round 17 (best measured: 165.4us). Round 18 (top-2)
// grew the rescan tail +20us; round 19 (NSLICE=64) regressed nnA +9us by
// doubling per-block fixed costs (x-frag build, prologue, epilogue, pv I/O).
// Config space is locally optimal at {top-3, NSLICE=32, (256,3), task tail}.

#define NQ 8192
#define NM 32768
#define ND 128
#define BT 256                // nnA block: 4 waves
#define NSLICE 32
#define SLICE (NM / NSLICE)   // 1024 rows -> 16 chunks of 64
#define QW 64                 // queries per wave
#define QB (QW * 4)           // 256 queries per block
#define CAPS 131072
#define CAPR 32768
#define PREP_YB 512
#define PREP_XB 128

using bf16x8 = __attribute__((ext_vector_type(8))) short;
using f32x4  = __attribute__((ext_vector_type(4))) float;

__device__ __forceinline__ unsigned short bf16r(float f) {
  unsigned u = __float_as_uint(f);
  u += 0x7FFFu + ((u >> 16) & 1u);
  return (unsigned short)(u >> 16);
}
__device__ __forceinline__ float bf2f(unsigned short h) {
  return __uint_as_float(((unsigned)h) << 16);
}
__device__ __forceinline__ unsigned long long packsd(float s, int j) {
  unsigned u = __float_as_uint(s);
  u ^= (u & 0x80000000u) ? 0xFFFFFFFFu : 0x80000000u;  // monotone float->uint
  return (((unsigned long long)u) << 32) | (unsigned)j;
}
__device__ __forceinline__ void gload_lds16(const void* g, void* l) {
  __builtin_amdgcn_global_load_lds(
      (const __attribute__((address_space(1))) void*)g,
      (__attribute__((address_space(3))) void*)l, 16, 0, 0);
}

// ---- prep: y -> packed bf16 hi ypk[rg][ks][lane][8], h[j]=0.5||y||^2,
//      global maxes of ||y||^2/||ylo||^2; x -> per-query ||x||^2, ||xlo||^2.
__global__ __launch_bounds__(256) void prep_kernel(
    const float* __restrict__ y, const float* __restrict__ x,
    unsigned short* __restrict__ ypk, float* __restrict__ h,
    float* __restrict__ x2, float* __restrict__ xlo2,
    unsigned* __restrict__ scal, int* __restrict__ cnts) {
  const int wv = threadIdx.x >> 6, l = threadIdx.x & 63;
  if (blockIdx.x == 0 && threadIdx.x == 0) { cnts[0] = 0; cnts[1] = 0; }
  if (blockIdx.x < PREP_YB) {
    __shared__ float bm[4][2];
    float ms = 0.f, mslo = 0.f;
    const int j00 = blockIdx.x * 64 + wv * 16;
#pragma unroll
    for (int r = 0; r < 16; ++r) {
      const int j = j00 + r;
      const float2 v = *(const float2*)(y + (size_t)j * ND + l * 2);
      const unsigned short hb0 = bf16r(v.x), hb1 = bf16r(v.y);
      const float lo0 = v.x - bf2f(hb0), lo1 = v.y - bf2f(hb1);
      const int c0 = l * 2;
      const int idx = ((j >> 4) * 2048) + ((c0 >> 5) * 512) +
                      ((((c0 >> 3) & 3) * 16 + (j & 15)) * 8) + (c0 & 7);
      *(unsigned*)&ypk[idx] = (unsigned)hb0 | ((unsigned)hb1 << 16);
      float s = fmaf(v.y, v.y, v.x * v.x);
      float slo = fmaf(lo1, lo1, lo0 * lo0);
      for (int off = 32; off; off >>= 1) {
        s += __shfl_xor(s, off);
        slo += __shfl_xor(slo, off);
      }
      if (l == 0) h[j] = 0.5f * s;
      ms = fmaxf(ms, s);
      mslo = fmaxf(mslo, slo);
    }
    if (l == 0) { bm[wv][0] = ms; bm[wv][1] = mslo; }
    __syncthreads();
    if (threadIdx.x == 0) {
      float a = bm[0][0], b = bm[0][1];
#pragma unroll
      for (int w2 = 1; w2 < 4; ++w2) { a = fmaxf(a, bm[w2][0]); b = fmaxf(b, bm[w2][1]); }
      atomicMax(&scal[0], __float_as_uint(a));
      atomicMax(&scal[1], __float_as_uint(b));
    }
  } else {
    const int q00 = (blockIdx.x - PREP_YB) * 64 + wv * 16;
#pragma unroll
    for (int r = 0; r < 16; ++r) {
      const int q = q00 + r;
      const float2 v = *(const float2*)(x + (size_t)q * ND + l * 2);
      const unsigned short hb0 = bf16r(v.x), hb1 = bf16r(v.y);
      const float lo0 = v.x - bf2f(hb0), lo1 = v.y - bf2f(hb1);
      float s = fmaf(v.y, v.y, v.x * v.x);
      float slo = fmaf(lo1, lo1, lo0 * lo0);
      for (int off = 32; off; off >>= 1) {
        s += __shfl_xor(s, off);
        slo += __shfl_xor(slo, off);
      }
      if (l == 0) { x2[q] = s; xlo2[q] = slo; }
    }
  }
}

// ---- pass A ----
// LDS chunk (shorts): [rg(4)][ks(4)][lane(64)][8] = 8192 shorts = 16KB.
#define LDFR(FH, ST) do {                                                      \
    _Pragma("unroll")                                                          \
    for (int ks = 0; ks < 4; ++ks)                                            \
      FH[ks] = *(const bf16x8*)&bufc[(ST) * 2048 + ks * 512 + lane * 8];       \
  } while (0)

#define MFST(FH, ST) do {                                                      \
    const float K_ = hv[ST];                                                   \
    f32x4 a0 = {K_, K_, K_, K_}, a1 = {K_, K_, K_, K_};                        \
    f32x4 a2 = {K_, K_, K_, K_}, a3 = {K_, K_, K_, K_};                        \
    __builtin_amdgcn_s_setprio(1);                                             \
    _Pragma("unroll")                                                          \
    for (int ks = 0; ks < 4; ++ks) {                                           \
      a0 = __builtin_amdgcn_mfma_f32_16x16x32_bf16(xn_[0][ks], FH[ks], a0, 0, 0, 0); \
      a1 = __builtin_amdgcn_mfma_f32_16x16x32_bf16(xn_[1][ks], FH[ks], a1, 0, 0, 0); \
      a2 = __builtin_amdgcn_mfma_f32_16x16x32_bf16(xn_[2][ks], FH[ks], a2, 0, 0, 0); \
      a3 = __builtin_amdgcn_mfma_f32_16x16x32_bf16(xn_[3][ks], FH[ks], a3, 0, 0, 0); \
    }                                                                          \
    __builtin_amdgcn_s_setprio(0);                                             \
    const unsigned jc_ = (unsigned)((it * 64 + (ST) * 16 + l15) & (SLICE - 1));\
    _Pragma("unroll")                                                          \
    for (int p = 0; p < 16; ++p) {                                             \
      const float aa = (p < 4) ? a0[p & 3] : (p < 8) ? a1[p & 3]               \
                       : (p < 12) ? a2[p & 3] : a3[p & 3];                     \
      const float key = __uint_as_float(                                       \
          (__float_as_uint(aa) & 0xFFFFFC00u) | jc_);  /* v_bfi */             \
      v3[p] = __builtin_amdgcn_fmed3f(v2[p], v3[p], key);                      \
      v2[p] = __builtin_amdgcn_fmed3f(v1[p], v2[p], key);                      \
      v1[p] = fminf(v1[p], key);                                               \
    }                                                                          \
  } while (0)

__global__ __launch_bounds__(BT, 3) void nnA_mfma(
    const float* __restrict__ x, const unsigned short* __restrict__ ypk,
    const float* __restrict__ h,
    float* __restrict__ pv1, float* __restrict__ pv2, float* __restrict__ pv3) {
  __shared__ unsigned short yl2[2][8192];  // double-buffered 64-row chunk, 4-wave shared
  const int t = threadIdx.x, lane = t & 63, w = t >> 6;
  const int l15 = lane & 15, lg = lane >> 4;
  const int slice = (blockIdx.x & 7) + 8 * ((blockIdx.x >> 3) & 3);  // XCD-pinned
  const int q0 = (blockIdx.x >> 5) * QB + w * QW;  // this wave's 64 queries

  // NEGATED x hi fragments (A-frag row=query l15, k=ks*32+lg*8+i)
  bf16x8 xn_[4][4];
#pragma unroll
  for (int qt = 0; qt < 4; ++qt)
#pragma unroll
    for (int ks = 0; ks < 4; ++ks) {
      const float* xp = x + (size_t)(q0 + qt * 16 + l15) * ND + ks * 32 + lg * 8;
      const float4 f0 = *(const float4*)xp;
      const float4 f1 = *(const float4*)(xp + 4);
      const float ff[8] = {f0.x, f0.y, f0.z, f0.w, f1.x, f1.y, f1.z, f1.w};
      bf16x8 vh;
#pragma unroll
      for (int i = 0; i < 8; ++i)
        vh[i] = (short)(bf16r(ff[i]) ^ 0x8000u);  // bf16 negate = sign flip
      xn_[qt][ks] = vh;
    }

  float v1[16], v2[16], v3[16];
#pragma unroll
  for (int p = 0; p < 16; ++p) { v1[p] = 3.4e38f; v2[p] = 3.4e38f; v3[p] = 3.4e38f; }

  const size_t sbase = (size_t)slice * (SLICE / 16) * 2048;
  // Prologue: 4 waves cooperatively stage chunk 0 (each 2048 shorts).
  {
    const unsigned short* src = ypk + sbase + w * 2048 + lane * 8;
#pragma unroll
    for (int s = 0; s < 4; ++s)
      gload_lds16(src + s * 512, &yl2[0][w * 2048 + s * 512]);
  }
  __syncthreads();

#pragma unroll 1
  for (int it = 0; it < SLICE / 64; ++it) {
    const int cur = it & 1;
    if (it < SLICE / 64 - 1) {
      const unsigned short* src =
          ypk + sbase + (size_t)(it + 1) * 8192 + w * 2048 + lane * 8;
      unsigned short* dst = &yl2[cur ^ 1][w * 2048];
#pragma unroll
      for (int s = 0; s < 4; ++s)
        gload_lds16(src + s * 512, dst + s * 512);
    }
    const int jb = slice * SLICE + it * 64;
    float hv[4];
#pragma unroll
    for (int st = 0; st < 4; ++st) hv[st] = h[jb + st * 16 + l15] + 512.0f;

    const unsigned short* __restrict__ bufc = &yl2[cur][0];
    bf16x8 FA[4];
    LDFR(FA, 0); MFST(FA, 0);
    LDFR(FA, 1); MFST(FA, 1);
    LDFR(FA, 2); MFST(FA, 2);
    LDFR(FA, 3); MFST(FA, 3);
    __syncthreads();
  }

  // Lane-16 top-3 merge network (keys positive w/ stuffed idx: min = lex min).
#pragma unroll
  for (int p = 0; p < 16; ++p) {
    float m1 = v1[p], m2 = v2[p], m3 = v3[p];
    for (int off = 1; off < 16; off <<= 1) {
      const float o1 = __shfl_xor(m1, off);
      const float o2 = __shfl_xor(m2, off);
      const float o3 = __shfl_xor(m3, off);
      const float n1 = fminf(m1, o1);
      const float n2 = __builtin_amdgcn_fmed3f(m1, o1, fminf(m2, o2));
      const float n3 = fminf(__builtin_amdgcn_fmed3f(m2, o2, fmaxf(m1, o1)),
                             fminf(m3, o3));
      m1 = n1; m2 = n2; m3 = n3;
    }
    if (l15 == 0) {
      const int q = q0 + (p >> 2) * 16 + lg * 4 + (p & 3);
      // TRANSPOSED layout [slice][NQ]: nnB reads are coalesced.
      pv1[(size_t)slice * NQ + q] = m1;
      pv2[(size_t)slice * NQ + q] = m2;
      pv3[(size_t)slice * NQ + q] = m3;
    }
  }
}

// exact fp32 key; k-ascending serial chain (nnB overflow path only)
__device__ __forceinline__ unsigned long long exact_key(
    const float* __restrict__ x, const float* __restrict__ y,
    const float* __restrict__ h, int q, int j) {
  const float* xp = x + (size_t)q * ND;
  const float* yp = y + (size_t)j * ND;
  float dot = 0.f;
#pragma unroll
  for (int k = 0; k < ND; ++k) dot = fmaf(xp[k], yp[k], dot);
  return packsd(h[j] - dot, j);
}

// ---- pass B: classify; explicit pairs from stuffed indices; rare rescans ----
__global__ void nnB_kernel(const float* __restrict__ x, const float* __restrict__ y,
                           const float* __restrict__ h, const float* __restrict__ lab,
                           const float* __restrict__ pv1, const float* __restrict__ pv2,
                           const float* __restrict__ pv3,
                           const float* __restrict__ x2, const float* __restrict__ xlo2,
                           const unsigned* __restrict__ scal,
                           float* __restrict__ out,
                           unsigned long long* __restrict__ packed,
                           int* __restrict__ mode, int* __restrict__ wlS,
                           int* __restrict__ wlR, int* __restrict__ cnts) {
  const int q = blockIdx.x * blockDim.x + threadIdx.x;
  if (q >= NQ) return;
  const float maxY = sqrtf(__uint_as_float(scal[0]));
  const float maxYlo = sqrtf(__uint_as_float(scal[1]));
  const float ex = sqrtf(x2[q]), exl = sqrtf(xlo2[q]);
  // hard bound: |key-(512+D)| <= CS; +0.08 = proven key-quant slack + margin.
  const float epsq = 2.0f * ((ex + exl) * maxYlo + exl * maxY) * 1.01f + 0.08f;
  float m = 3.4e38f;
  for (int s = 0; s < NSLICE; ++s) m = fminf(m, pv1[(size_t)s * NQ + q]);
  const float thr = m + epsq;
  int pj[2 * NSLICE], rs[NSLICE], np = 0, nr = 0;
  for (int s = 0; s < NSLICE; ++s) {
    const float p1 = pv1[(size_t)s * NQ + q];
    if (p1 <= thr) {
      if (pv3[(size_t)s * NQ + q] <= thr) {
        rs[nr++] = s;  // >=3 candidates in slice (rare): rescan
      } else {
        pj[np++] = s * SLICE + (int)(__float_as_uint(p1) & (SLICE - 1));
        const float p2 = pv2[(size_t)s * NQ + q];
        if (p2 <= thr)
          pj[np++] = s * SLICE + (int)(__float_as_uint(p2) & (SLICE - 1));
      }
    }
  }
  if (nr == 0 && np == 1) { out[q] = lab[pj[0]]; mode[q] = 0; return; }
  mode[q] = 1;
  packed[q] = ~0ull;
  const int baseS = atomicAdd(&cnts[0], np);
  for (int i = 0; i < np; ++i)
    if (baseS + i < CAPS) wlS[baseS + i] = (q << 15) | pj[i];
  const int baseR = atomicAdd(&cnts[1], nr);
  for (int i = 0; i < nr; ++i)
    if (baseR + i < CAPR) wlR[baseR + i] = (q << 5) | rs[i];
  if (baseS + np > CAPS || baseR + nr > CAPR) {
    // overflow safety (practically never): resolve fully serial, exact
    unsigned long long b = ~0ull;
    for (int i = 0; i < np; ++i) {
      const unsigned long long k = exact_key(x, y, h, q, pj[i]);
      b = k < b ? k : b;
    }
    for (int i = 0; i < nr; ++i)
      for (int j = rs[i] * SLICE; j < rs[i] * SLICE + SLICE; ++j) {
        const unsigned long long k = exact_key(x, y, h, q, j);
        b = k < b ? k : b;
      }
    out[q] = lab[(unsigned)(b & 0xFFFFFFFFull)];
    mode[q] = 0;
  }
}

// ---- pass S: wave-per-(q,j) exact dot (coalesced), atomicMin ----
__global__ __launch_bounds__(256) void nnS_kernel(
    const float* __restrict__ x, const float* __restrict__ y,
    const float* __restrict__ h, const int* __restrict__ wlS,
    const int* __restrict__ cnts, unsigned long long* __restrict__ packed) {
  int n = cnts[0];
  if (n > CAPS) n = CAPS;
  const int l = threadIdx.x & 63;
  const int wid = (blockIdx.x * blockDim.x + threadIdx.x) >> 6;
  const int nw = (gridDim.x * blockDim.x) >> 6;
  for (int e = wid; e < n; e += nw) {
    const int v = wlS[e];
    const int q = v >> 15, j = v & (NM - 1);
    const float2 xv = *(const float2*)(x + (size_t)q * ND + l * 2);
    const float2 yv = *(const float2*)(y + (size_t)j * ND + l * 2);
    float d = fmaf(xv.y, yv.y, xv.x * yv.x);
    for (int off = 32; off; off >>= 1) d += __shfl_xor(d, off);
    if (l == 0) atomicMin(packed + q, packsd(h[j] - d, j));
  }
}

// ---- pass C: rescans, TASK-PARALLEL: (entry x 64 row-groups) wave-tasks.
//      Each task: 16 coalesced row-dots (unrolled -> ILP), one atomicMin.
__global__ __launch_bounds__(256) void nnC_kernel(
    const float* __restrict__ x, const float* __restrict__ y,
    const float* __restrict__ h, const int* __restrict__ wlR,
    const int* __restrict__ cnts, unsigned long long* __restrict__ packed) {
  int n = cnts[1];
  if (n > CAPR) n = CAPR;
  const long long ntask = (long long)n * (SLICE / 16);
  const int l = threadIdx.x & 63;
  const int wid = (blockIdx.x * blockDim.x + threadIdx.x) >> 6;
  const int nw = (gridDim.x * blockDim.x) >> 6;
  for (long long tsk = wid; tsk < ntask; tsk += nw) {
    const int e = (int)(tsk >> 6), rg = (int)(tsk & 63);
    const int v = wlR[e], q = v >> 5, sl = v & (NSLICE - 1);
    const float2 xv = *(const float2*)(x + (size_t)q * ND + l * 2);
    const int j0 = sl * SLICE + rg * 16;
    unsigned long long best = ~0ull;
#pragma unroll
    for (int r = 0; r < 16; ++r) {
      const int j = j0 + r;
      const float2 yv = *(const float2*)(y + (size_t)j * ND + l * 2);
      float d = fmaf(xv.y, yv.y, xv.x * yv.x);
      for (int off = 32; off; off >>= 1) d += __shfl_xor(d, off);
      const unsigned long long kk = packsd(h[j] - d, j);
      if (kk < best) best = kk;  // butterfly leaves the full sum in all lanes
    }
    if (l == 0) atomicMin(packed + q, best);
  }
}

// ---- pass D: finalize pending queries ----
__global__ void nnD_kernel(const unsigned long long* __restrict__ packed,
                           const int* __restrict__ mode,
                           const float* __restrict__ lab, float* __restrict__ out) {
  const int q = blockIdx.x * blockDim.x + threadIdx.x;
  if (q >= NQ) return;
  if (mode[q]) out[q] = lab[(unsigned)(packed[q] & 0xFFFFFFFFull)];
}

// ---- fallback (round-2 kernel, known-passing) ----
__global__ void hrow_fb(const float* __restrict__ y, float* __restrict__ h) {
  const int j = blockIdx.x * blockDim.x + threadIdx.x;
  if (j >= NM) return;
  const float4* __restrict__ yp = (const float4*)(y + (size_t)j * ND);
  float s = 0.f;
#pragma unroll
  for (int u = 0; u < ND / 4; ++u) {
    const float4 v = yp[u];
    s = fmaf(v.x, v.x, s); s = fmaf(v.y, v.y, s);
    s = fmaf(v.z, v.z, s); s = fmaf(v.w, v.w, s);
  }
  h[j] = 0.5f * s;
}

template <int USE_H>
__global__ __launch_bounds__(256, 2) void nn_fallback(
    const float* __restrict__ x, const float* __restrict__ y,
    const float* __restrict__ lab, const float* __restrict__ h,
    float* __restrict__ out) {
  const int t = threadIdx.x;
  const int q0 = blockIdx.x * 16;
  float bv[16]; int bi[16];
#pragma unroll
  for (int q = 0; q < 16; ++q) { bv[q] = 3.4e38f; bi[q] = 0; }
  for (int it = 0; it < NM / 512; ++it) {
    const int j0 = it * 512 + t, j1 = j0 + 256;
    const float4* __restrict__ yp0 = (const float4*)(y + (size_t)j0 * ND);
    const float4* __restrict__ yp1 = (const float4*)(y + (size_t)j1 * ND);
    float acc0[16], acc1[16];
#pragma unroll
    for (int q = 0; q < 16; ++q) { acc0[q] = 0.f; acc1[q] = 0.f; }
    float y20 = 0.f, y21 = 0.f;
#pragma unroll 1
    for (int kc = 0; kc < 4; ++kc) {
      float4 a0[8], a1[8];
#pragma unroll
      for (int u = 0; u < 8; ++u) { a0[u] = yp0[kc * 8 + u]; a1[u] = yp1[kc * 8 + u]; }
      if (USE_H == 0) {
#pragma unroll
        for (int u = 0; u < 8; ++u) {
          y20 = fmaf(a0[u].x, a0[u].x, y20); y20 = fmaf(a0[u].y, a0[u].y, y20);
          y20 = fmaf(a0[u].z, a0[u].z, y20); y20 = fmaf(a0[u].w, a0[u].w, y20);
          y21 = fmaf(a1[u].x, a1[u].x, y21); y21 = fmaf(a1[u].y, a1[u].y, y21);
          y21 = fmaf(a1[u].z, a1[u].z, y21); y21 = fmaf(a1[u].w, a1[u].w, y21);
        }
      }
#pragma unroll
      for (int q = 0; q < 16; ++q) {
        const float* __restrict__ xq = x + (size_t)(q0 + q) * ND + kc * 32;
        float s0 = acc0[q], s1 = acc1[q];
#pragma unroll
        for (int u = 0; u < 8; ++u) {
          const float4 xv = *(const float4*)(xq + u * 4);
          s0 = fmaf(a0[u].x, xv.x, s0); s0 = fmaf(a0[u].y, xv.y, s0);
          s0 = fmaf(a0[u].z, xv.z, s0); s0 = fmaf(a0[u].w, xv.w, s0);
          s1 = fmaf(a1[u].x, xv.x, s1); s1 = fmaf(a1[u].y, xv.y, s1);
          s1 = fmaf(a1[u].z, xv.z, s1); s1 = fmaf(a1[u].w, xv.w, s1);
        }
        acc0[q] = s0; acc1[q] = s1;
      }
    }
    float h0, h1;
    if (USE_H) { h0 = h[j0]; h1 = h[j1]; }
    else { h0 = 0.5f * y20; h1 = 0.5f * y21; }
#pragma unroll
    for (int q = 0; q < 16; ++q) {
      const float s0 = h0 - acc0[q], s1 = h1 - acc1[q];
      if (s0 < bv[q]) { bv[q] = s0; bi[q] = j0; }
      if (s1 < bv[q]) { bv[q] = s1; bi[q] = j1; }
    }
  }
  __shared__ float rv[4][16];
  __shared__ int ri[4][16];
  const int lane = t & 63, w = t >> 6;
#pragma unroll
  for (int q = 0; q < 16; ++q) {
    float v = bv[q]; int ixq = bi[q];
    for (int off = 32; off; off >>= 1) {
      const float ov = __shfl_down(v, off);
      const int oi = __shfl_down(ixq, off);
      if (ov < v || (ov == v && oi < ixq)) { v = ov; ixq = oi; }
    }
    if (lane == 0) { rv[w][q] = v; ri[w][q] = ixq; }
  }
  __syncthreads();
  if (t < 16) {
    float v = rv[0][t]; int ixq = ri[0][t];
#pragma unroll
    for (int w2 = 1; w2 < 4; ++w2) {
      const float ov = rv[w2][t]; const int oi = ri[w2][t];
      if (ov < v || (ov == v && oi < ixq)) { v = ov; ixq = oi; }
    }
    out[q0 + t] = lab[ixq];
  }
}

extern "C" void kernel_launch(void* const* d_in, const int* in_sizes, int n_in,
                              void* d_out, int out_size, void* d_ws, size_t ws_size,
                              hipStream_t stream) {
  const float* x = (const float*)d_in[0];
  const float* y = (const float*)d_in[1];
  const float* lab = (const float*)d_in[2];
  float* out = (float*)d_out;

  const size_t o_ypk = 0;                                // 8 MB hi-only packed
  const size_t o_h   = o_ypk + (size_t)NM * ND * 2;
  const size_t o_x2  = o_h + (size_t)NM * 4;
  const size_t o_xl2 = o_x2 + (size_t)NQ * 4;
  const size_t o_sc  = o_xl2 + (size_t)NQ * 4;
  const size_t o_p1  = o_sc + 16;
  const size_t o_p2  = o_p1 + (size_t)NQ * NSLICE * 4;   // 1 MB each
  const size_t o_p3  = o_p2 + (size_t)NQ * NSLICE * 4;
  const size_t o_pk  = o_p3 + (size_t)NQ * NSLICE * 4;
  const size_t o_wlS = o_pk + (size_t)NQ * 8;
  const size_t o_wlR = o_wlS + (size_t)CAPS * 4;
  const size_t o_md  = o_wlR + (size_t)CAPR * 4;
  const size_t o_ct  = o_md + (size_t)NQ * 4;
  const size_t need  = o_ct + 16;

  if (ws_size >= need) {
    char* W = (char*)d_ws;
    unsigned short* ypk = (unsigned short*)(W + o_ypk);
    float* h = (float*)(W + o_h);
    float* x2 = (float*)(W + o_x2);
    float* xlo2 = (float*)(W + o_xl2);
    unsigned* scal = (unsigned*)(W + o_sc);
    float* pv1 = (float*)(W + o_p1);
    float* pv2 = (float*)(W + o_p2);
    float* pv3 = (float*)(W + o_p3);
    unsigned long long* packed = (unsigned long long*)(W + o_pk);
    int* wlS = (int*)(W + o_wlS);
    int* wlR = (int*)(W + o_wlR);
    int* mode = (int*)(W + o_md);
    int* cnts = (int*)(W + o_ct);
    hipMemsetAsync(scal, 0, 16, stream);
    prep_kernel<<<PREP_YB + PREP_XB, 256, 0, stream>>>(y, x, ypk, h, x2, xlo2,
                                                       scal, cnts);
    nnA_mfma<<<(NQ / QB) * NSLICE, BT, 0, stream>>>(x, ypk, h, pv1, pv2, pv3);
    nnB_kernel<<<NQ / 256, 256, 0, stream>>>(x, y, h, lab, pv1, pv2, pv3,
                                             x2, xlo2, scal, out, packed, mode,
                                             wlS, wlR, cnts);
    nnS_kernel<<<256, 256, 0, stream>>>(x, y, h, wlS, cnts, packed);
    nnC_kernel<<<256, 256, 0, stream>>>(x, y, h, wlR, cnts, packed);
    nnD_kernel<<<NQ / 256, 256, 0, stream>>>(packed, mode, lab, out);
  } else if (ws_size >= (size_t)NM * 4) {
    float* h = (float*)d_ws;
    hrow_fb<<<NM / 256, 256, 0, stream>>>(y, h);
    nn_fallback<1><<<NQ / 16, 256, 0, stream>>>(x, y, lab, h, out);
  } else {
    nn_fallback<0><<<NQ / 16, 256, 0, stream>>>(x, y, lab, nullptr, out);
  }
}